// Round 6
// baseline (236.434 us; speedup 1.0000x reference)
//
#include <hip/hip_runtime.h>
#include <math.h>

#define D   128
#define LQ  256
#define KCQ 9
#define BQ  8
#define TQ  4096
#define RISK_DELTA 2e-5f
#define WCAP 16384

// ---------------- precompute kernels (weights-only, tiny, all-double) ----------------
__global__ void pk1(const float* __restrict__ wk, const float* __restrict__ wq,
                    const float* __restrict__ ctx_w, const float* __restrict__ bias_w,
                    double* __restrict__ T2, double* __restrict__ u, int* __restrict__ wcnt) {
    int e = threadIdx.x;
    if (blockIdx.x < D) {
        int d = blockIdx.x;
        double acc = 0.0;
        for (int j = 0; j < D; ++j)
            acc += (double)wk[j * D + d] * (double)wq[j * D + e];
        T2[d * D + e] = acc;
    } else if (blockIdx.x == D) {
        double acc = 0.0;
        for (int dd = 0; dd < D; ++dd)
            acc += (double)bias_w[dd] * (double)ctx_w[dd * D + e];
        u[e] = acc;
    } else {
        if (e == 0) *wcnt = 0;
    }
}

__global__ void pk2(const double* __restrict__ T2, const float* __restrict__ ctx_w,
                    const float* __restrict__ conv_w, const float* __restrict__ conv_b,
                    const float* __restrict__ ctx_b,
                    double* __restrict__ g, double* __restrict__ c1) {
    __shared__ double row[D];
    int d = blockIdx.x, e = threadIdx.x;
    double acc = 0.0;
    for (int j = 0; j < D; ++j)
        acc += T2[d * D + j] * (double)ctx_w[j * D + e];
    row[e] = acc;
    __syncthreads();
    if (e < KCQ) {
        double a = 0.0;
        for (int q = 0; q < D; ++q) a += row[q] * (double)conv_w[q * KCQ + e];
        g[e * D + d] = a;           // tap-major: g[k][d]
    } else if (e == KCQ) {
        double a = 0.0;
        for (int q = 0; q < D; ++q) a += row[q] * (double)conv_b[q];
        for (int q = 0; q < D; ++q) a += T2[d * D + q] * (double)ctx_b[q];
        c1[d] = a;
    }
}

__global__ void pk3(const float* __restrict__ lag_embed, const float* __restrict__ val_b,
                    const float* __restrict__ val_w, const float* __restrict__ conv_w,
                    const float* __restrict__ conv_b, const float* __restrict__ ctx_b,
                    const float* __restrict__ bias_w, const float* __restrict__ bias_b,
                    const double* __restrict__ g, const double* __restrict__ c1,
                    const double* __restrict__ u,
                    double* __restrict__ gbT, double* __restrict__ cbv, double* __restrict__ cst) {
    int tid = threadIdx.x;
    if (blockIdx.x < LQ) {
        __shared__ double bl[D];
        int l = blockIdx.x;
        bl[tid] = (double)val_b[tid] + (double)lag_embed[(l + 1) * D + tid];
        __syncthreads();
        if (tid < KCQ) {
            double a = 0.0;
            for (int q = 0; q < D; ++q) a += bl[q] * g[tid * D + q];
            gbT[tid * LQ + l] = a;
        } else if (tid == KCQ) {
            double a = 0.0;
            for (int q = 0; q < D; ++q) a += bl[q] * c1[q];
            cbv[l] = a;
        }
    } else {
        if (tid < KCQ) {
            double a = 0.0, a2 = 0.0;
            for (int q = 0; q < D; ++q) a  += g[tid * D + q] * (double)val_w[q];
            for (int q = 0; q < D; ++q) a2 += u[q] * (double)conv_w[q * KCQ + tid];
            cst[tid]      = a;    // sk[k]
            cst[10 + tid] = a2;   // hk[k]
        } else if (tid == KCQ) {
            double a = 0.0, a2 = 0.0;
            for (int q = 0; q < D; ++q) a  += c1[q] * (double)val_w[q];
            for (int q = 0; q < D; ++q) a2 += u[q] * (double)conv_b[q];
            for (int q = 0; q < D; ++q) a2 += (double)bias_w[q] * (double)ctx_b[q];
            cst[9]  = a;                          // ssc
            cst[19] = a2 + (double)bias_b[0];     // hc (incl. bias_b)
        }
    }
}

// pk4: transposed f32 tables so the fixer's loads are lane-coalesced.
__global__ void pk4(const float* __restrict__ ctx_w, const float* __restrict__ wq,
                    const float* __restrict__ conv_w, const float* __restrict__ val_b,
                    const float* __restrict__ lag_embed,
                    float* __restrict__ ctx_wT, float* __restrict__ wqT,
                    float* __restrict__ conv_wT, float* __restrict__ baseT) {
    int d2 = blockIdx.x;        // 0..127
    int tid = threadIdx.x;      // 0..255
    if (tid < D) {
        ctx_wT[d2 * D + tid] = ctx_w[tid * D + d2];
        wqT[d2 * D + tid]    = wq[tid * D + d2];
        if (d2 < KCQ) conv_wT[d2 * D + tid] = conv_w[tid * KCQ + d2];
    }
    // baseT[d2][l] = f32(val_b[d2] + lag_embed[l+1][d2]) — same __fadd_rn as fixer used
    baseT[d2 * LQ + tid] = __fadd_rn(val_b[d2], lag_embed[(size_t)(tid + 1) * D + d2]);
}

// ---------------- main kernel: 16-lane groups, 4 rows/wave, 16 rows/block ----------
// Lane gl (0..15) of group g owns lags l = gl*16 .. gl*16+15.
// Padded LDS layout: lag l stored at dword (l>>4)*20 + (l&15)  (16B-aligned float4 reads).
__global__ __launch_bounds__(256, 4) void lag_main(
    const float* __restrict__ x, const double* __restrict__ gbT,
    const double* __restrict__ cbv, const double* __restrict__ cst,
    float* __restrict__ muOut, float* __restrict__ wOut,
    int* __restrict__ wcnt, int* __restrict__ wlist) {
    __shared__ __align__(16) float sgb[KCQ][320];
    __shared__ __align__(16) float scb[320];
    __shared__ float sc[20];
    int tid = threadIdx.x;
    {
        int pidx = ((tid >> 4) * 20) + (tid & 15);
        #pragma unroll
        for (int k = 0; k < KCQ; ++k) sgb[k][pidx] = (float)gbT[k * LQ + tid];
        scb[pidx] = (float)cbv[tid];
        if (tid < 20) sc[tid] = (float)cst[tid];
    }
    __syncthreads();

    int wave = tid >> 6, lane = tid & 63;
    int g = lane >> 4, gl = lane & 15;
    int row = blockIdx.x * 16 + wave * 4 + g;
    int b = row >> 12;
    int t = row & (TQ - 1);
    const float* xb = x + b * TQ;

    // 9-sample window x[t-8..t]
    float xw[KCQ];
    #pragma unroll
    for (int k = 0; k < KCQ; ++k) {
        int idx = t - 8 + k;
        xw[k] = (idx >= 0) ? xb[idx] : 0.f;
    }
    float s = sc[9], bias = sc[19];
    #pragma unroll
    for (int k = 0; k < KCQ; ++k) {
        s    = fmaf(sc[k],      xw[k], s);
        bias = fmaf(sc[10 + k], xw[k], bias);
    }

    int l0 = gl * 16;
    int pbase = gl * 20;

    // logits: same value/order as round 5 (init cb, fmaf taps k ascending, + xlag*s)
    float lg[16];
    #pragma unroll
    for (int jj = 0; jj < 4; ++jj) {
        float4 c4 = *reinterpret_cast<const float4*>(&scb[pbase + 4 * jj]);
        lg[4 * jj + 0] = c4.x; lg[4 * jj + 1] = c4.y;
        lg[4 * jj + 2] = c4.z; lg[4 * jj + 3] = c4.w;
    }
    #pragma unroll
    for (int k = 0; k < KCQ; ++k) {
        float xk = xw[k];
        #pragma unroll
        for (int jj = 0; jj < 4; ++jj) {
            float4 g4 = *reinterpret_cast<const float4*>(&sgb[k][pbase + 4 * jj]);
            lg[4 * jj + 0] = fmaf(g4.x, xk, lg[4 * jj + 0]);
            lg[4 * jj + 1] = fmaf(g4.y, xk, lg[4 * jj + 1]);
            lg[4 * jj + 2] = fmaf(g4.z, xk, lg[4 * jj + 2]);
            lg[4 * jj + 3] = fmaf(g4.w, xk, lg[4 * jj + 3]);
        }
    }
    float xlag[16];
    #pragma unroll
    for (int j = 0; j < 16; ++j) {
        int idx = t - 1 - (l0 + j);
        xlag[j] = (idx >= 0) ? xb[idx] : 0.f;
        lg[j] = fmaf(xlag[j], s, lg[j]);
    }

    // top-9 within the 16-lane group: mx (1st), thr (8th), v9 (9th).
    // Removal is ballot-free: clear ALL instances equal to m (ties measure-zero).
    const float NEG_INF = -__builtin_inff();
    float wl[16];
    #pragma unroll
    for (int j = 0; j < 16; ++j) wl[j] = lg[j];
    float mx = 0.f, thr = 0.f, v9 = 0.f;
    #pragma unroll
    for (int it = 0; it < 9; ++it) {
        // local max, tree (depth 4)
        float a0 = fmaxf(wl[0], wl[1]),  a1 = fmaxf(wl[2], wl[3]);
        float a2 = fmaxf(wl[4], wl[5]),  a3 = fmaxf(wl[6], wl[7]);
        float a4 = fmaxf(wl[8], wl[9]),  a5 = fmaxf(wl[10], wl[11]);
        float a6 = fmaxf(wl[12], wl[13]), a7 = fmaxf(wl[14], wl[15]);
        float b0 = fmaxf(a0, a1), b1 = fmaxf(a2, a3);
        float b2 = fmaxf(a4, a5), b3 = fmaxf(a6, a7);
        float m = fmaxf(fmaxf(b0, b1), fmaxf(b2, b3));
        // group (16-lane) reduce: xor offs 1,2,4,8 stay within the group
        m = fmaxf(m, __shfl_xor(m, 1, 64));
        m = fmaxf(m, __shfl_xor(m, 2, 64));
        m = fmaxf(m, __shfl_xor(m, 4, 64));
        m = fmaxf(m, __shfl_xor(m, 8, 64));
        if (it == 0) mx = m;
        if (it == 7) thr = m;
        if (it == 8) v9 = m;
        if (it < 8) {
            #pragma unroll
            for (int j = 0; j < 16; ++j)
                wl[j] = (wl[j] == m) ? NEG_INF : wl[j];
        }
    }

    // near-tie rows -> fixer (unless worklist full, then self-write)
    bool defer = false;
    if ((thr - v9) < RISK_DELTA) {
        int pos = 0;
        if (gl == 0) pos = atomicAdd(wcnt, 1);
        pos = __shfl(pos, lane & 48, 64);   // broadcast from group leader
        if (pos < WCAP) {
            if (gl == 0) wlist[pos] = row;
            defer = true;
        }
    }
    if (!defer) {
        float p[16];
        float psum = 0.f, pmu = 0.f;
        #pragma unroll
        for (int j = 0; j < 16; ++j) {
            p[j] = (lg[j] >= thr) ? __expf(lg[j] - mx) : 0.f;
            psum += p[j];
            pmu = fmaf(p[j], xlag[j], pmu);
        }
        psum += __shfl_xor(psum, 1, 64);  pmu += __shfl_xor(pmu, 1, 64);
        psum += __shfl_xor(psum, 2, 64);  pmu += __shfl_xor(pmu, 2, 64);
        psum += __shfl_xor(psum, 4, 64);  pmu += __shfl_xor(pmu, 4, 64);
        psum += __shfl_xor(psum, 8, 64);  pmu += __shfl_xor(pmu, 8, 64);
        float inv = 1.f / psum;
        #pragma unroll
        for (int jj = 0; jj < 4; ++jj) {
            float4 wo = make_float4(p[4 * jj] * inv, p[4 * jj + 1] * inv,
                                    p[4 * jj + 2] * inv, p[4 * jj + 3] * inv);
            *reinterpret_cast<float4*>(&wOut[(size_t)row * LQ + l0 + 4 * jj]) = wo;
        }
        if (gl == 0) muOut[row] = fmaf(pmu, inv, bias);
    }
}

// ---------------- fixer: np-faithful fp32 pipeline (sequential f32 FMA dots) --------
// Arithmetic identical to round 4/5 (proven arbiter-matcher); loads now coalesced
// via the pk4-transposed tables.
__global__ __launch_bounds__(256) void fixer(
    const float* __restrict__ x, const float* __restrict__ wk,
    const float* __restrict__ val_w, const float* __restrict__ conv_b,
    const float* __restrict__ ctx_b, const float* __restrict__ bias_w,
    const float* __restrict__ bias_b,
    const float* __restrict__ ctx_wT, const float* __restrict__ wqT,
    const float* __restrict__ conv_wT, const float* __restrict__ baseT,
    const int* __restrict__ wcnt, const int* __restrict__ wlist,
    float* __restrict__ muOut, float* __restrict__ wOut) {
    __shared__ float sxw[8][KCQ];
    __shared__ float sctxc[8][D];
    __shared__ float sctxp[8][D];
    __shared__ float sq[8][D];
    __shared__ float sqk[8][D];
    __shared__ float ssv[8];
    __shared__ float sbd[8];
    __shared__ float slog[8][LQ];
    __shared__ int   srow[8];

    int cnt = *wcnt;
    if (cnt > WCAP) cnt = WCAP;
    int ngroups = (cnt + 7) >> 3;
    int tid = threadIdx.x;

    for (int gi = blockIdx.x; gi < ngroups; gi += gridDim.x) {
        if (tid < 8) {
            int idx = gi * 8 + tid;
            if (idx >= cnt) idx = cnt - 1;   // pad with last row (duplicate write is benign)
            srow[tid] = wlist[idx];
        }
        __syncthreads();
        if (tid < 8 * KCQ) {
            int g = tid / KCQ, k = tid % KCQ;
            int row = srow[g]; int b = row >> 12, t = row & (TQ - 1);
            int ii = t - 8 + k;
            sxw[g][k] = (ii >= 0) ? x[b * TQ + ii] : 0.f;
        }
        __syncthreads();

        // stage 1: causal conv — sequential f32 FMA over k, then f32 add of conv_b
        {
            int d = tid & (D - 1), gh = tid >> 7;
            for (int g = gh * 4; g < gh * 4 + 4; ++g) {
                float a = 0.f;
                #pragma unroll
                for (int k = 0; k < KCQ; ++k)
                    a = fmaf(conv_wT[k * D + d], sxw[g][k], a);
                sctxc[g][d] = __fadd_rn(a, conv_b[d]);
            }
        }
        __syncthreads();

        // stage 2: ctx_proj — sequential f32 FMA over d, then + ctx_b
        {
            int e = tid & (D - 1), gh = tid >> 7, g0 = gh * 4;
            float a0 = 0.f, a1 = 0.f, a2 = 0.f, a3 = 0.f;
            for (int d2 = 0; d2 < D; ++d2) {
                float wv = ctx_wT[d2 * D + e];
                a0 = fmaf(wv, sctxc[g0 + 0][d2], a0);
                a1 = fmaf(wv, sctxc[g0 + 1][d2], a1);
                a2 = fmaf(wv, sctxc[g0 + 2][d2], a2);
                a3 = fmaf(wv, sctxc[g0 + 3][d2], a3);
            }
            float cb = ctx_b[e];
            sctxp[g0 + 0][e] = __fadd_rn(a0, cb);
            sctxp[g0 + 1][e] = __fadd_rn(a1, cb);
            sctxp[g0 + 2][e] = __fadd_rn(a2, cb);
            sctxp[g0 + 3][e] = __fadd_rn(a3, cb);
        }
        __syncthreads();

        // stage 3: q = ctx @ wq.T — sequential f32 FMA over e
        {
            int a = tid & (D - 1), gh = tid >> 7, g0 = gh * 4;
            float a0 = 0.f, a1 = 0.f, a2 = 0.f, a3 = 0.f;
            for (int e2 = 0; e2 < D; ++e2) {
                float wv = wqT[e2 * D + a];
                a0 = fmaf(wv, sctxp[g0 + 0][e2], a0);
                a1 = fmaf(wv, sctxp[g0 + 1][e2], a1);
                a2 = fmaf(wv, sctxp[g0 + 2][e2], a2);
                a3 = fmaf(wv, sctxp[g0 + 3][e2], a3);
            }
            sq[g0 + 0][a] = a0;
            sq[g0 + 1][a] = a1;
            sq[g0 + 2][a] = a2;
            sq[g0 + 3][a] = a3;
        }
        __syncthreads();

        // stage 4: qk = q @ wk — sequential f32 FMA over a (wk already coalesced)
        {
            int d = tid & (D - 1), gh = tid >> 7, g0 = gh * 4;
            float a0 = 0.f, a1 = 0.f, a2 = 0.f, a3 = 0.f;
            for (int a2i = 0; a2i < D; ++a2i) {
                float wv = wk[a2i * D + d];
                a0 = fmaf(wv, sq[g0 + 0][a2i], a0);
                a1 = fmaf(wv, sq[g0 + 1][a2i], a1);
                a2 = fmaf(wv, sq[g0 + 2][a2i], a2);
                a3 = fmaf(wv, sq[g0 + 3][a2i], a3);
            }
            sqk[g0 + 0][d] = a0;
            sqk[g0 + 1][d] = a1;
            sqk[g0 + 2][d] = a2;
            sqk[g0 + 3][d] = a3;
        }
        __syncthreads();

        // s = qk·val_w ; biasdot = ctxp·bias_w — sequential f32 FMA
        if (tid < 8) {
            int g = tid;
            float a = 0.f;
            for (int d2 = 0; d2 < D; ++d2) a = fmaf(sqk[g][d2], val_w[d2], a);
            ssv[g] = a;
        } else if (tid < 16) {
            int g = tid - 8;
            float a = 0.f;
            for (int e2 = 0; e2 < D; ++e2) a = fmaf(sctxp[g][e2], bias_w[e2], a);
            sbd[g] = a;
        }
        __syncthreads();

        // logits: blog[l] = Σ_d baseT[d][l]·qk[d] sequential f32 FMA (coalesced over l);
        // logit = f32(xlag*s) + blog
        {
            int l = tid;
            float c0 = 0.f, c1a = 0.f, c2 = 0.f, c3 = 0.f, c4 = 0.f, c5 = 0.f, c6 = 0.f, c7 = 0.f;
            for (int d2 = 0; d2 < D; ++d2) {
                float bd = baseT[d2 * LQ + l];
                c0 = fmaf(bd, sqk[0][d2], c0);
                c1a = fmaf(bd, sqk[1][d2], c1a);
                c2 = fmaf(bd, sqk[2][d2], c2);
                c3 = fmaf(bd, sqk[3][d2], c3);
                c4 = fmaf(bd, sqk[4][d2], c4);
                c5 = fmaf(bd, sqk[5][d2], c5);
                c6 = fmaf(bd, sqk[6][d2], c6);
                c7 = fmaf(bd, sqk[7][d2], c7);
            }
            float accs[8] = {c0, c1a, c2, c3, c4, c5, c6, c7};
            #pragma unroll
            for (int g = 0; g < 8; ++g) {
                int row = srow[g]; int b = row >> 12, t = row & (TQ - 1);
                int ii = t - 1 - l;
                float xl = (ii >= 0) ? x[b * TQ + ii] : 0.f;
                slog[g][l] = __fadd_rn(__fmul_rn(xl, ssv[g]), accs[g]);
            }
        }
        __syncthreads();

        // per-row f32 top-8 + f32 softmax + writes; wave handles 2 rows
        {
            int wave = tid >> 6, lane = tid & 63;
            for (int gg = wave * 2; gg < wave * 2 + 2; ++gg) {
                float lv0 = slog[gg][lane], lv1 = slog[gg][lane + 64];
                float lv2 = slog[gg][lane + 128], lv3 = slog[gg][lane + 192];
                const float NEG_INF = -__builtin_inff();
                float w0 = lv0, w1 = lv1, w2 = lv2, w3 = lv3;
                float mx = 0.f, thr = 0.f;
                #pragma unroll
                for (int it = 0; it < 8; ++it) {
                    float lm = fmaxf(fmaxf(w0, w1), fmaxf(w2, w3));
                    float m = lm;
                    #pragma unroll
                    for (int off = 32; off >= 1; off >>= 1)
                        m = fmaxf(m, __shfl_xor(m, off, 64));
                    if (it == 0) mx = m;
                    thr = m;
                    if (it < 7) {
                        unsigned long long ball = __ballot(lm == m);
                        int leader = __ffsll(ball) - 1;
                        if (lane == leader) {
                            if (w0 == m)      w0 = NEG_INF;
                            else if (w1 == m) w1 = NEG_INF;
                            else if (w2 == m) w2 = NEG_INF;
                            else              w3 = NEG_INF;
                        }
                    }
                }
                int row = srow[gg]; int b = row >> 12, t = row & (TQ - 1);
                float p[4], xlg[4];
                double ps = 0.0;
                float lvs[4] = {lv0, lv1, lv2, lv3};
                #pragma unroll
                for (int j = 0; j < 4; ++j) {
                    int l = lane + 64 * j;
                    int ii = t - 1 - l;
                    xlg[j] = (ii >= 0) ? x[b * TQ + ii] : 0.f;
                    p[j] = (lvs[j] >= thr) ? (float)exp((double)__fsub_rn(lvs[j], mx)) : 0.f;
                    ps += (double)p[j];
                }
                #pragma unroll
                for (int off = 32; off >= 1; off >>= 1)
                    ps += __shfl_xor(ps, off, 64);
                float psf = (float)ps;
                double mud = 0.0;
                #pragma unroll
                for (int j = 0; j < 4; ++j) {
                    float wv = __fdiv_rn(p[j], psf);
                    wOut[(size_t)row * LQ + lane + 64 * j] = wv;
                    mud += (double)__fmul_rn(wv, xlg[j]);
                }
                #pragma unroll
                for (int off = 32; off >= 1; off >>= 1)
                    mud += __shfl_xor(mud, off, 64);
                if (lane == 0) {
                    float m1 = (float)mud;
                    m1 = __fadd_rn(m1, sbd[gg]);
                    m1 = __fadd_rn(m1, bias_b[0]);
                    muOut[row] = m1;
                }
            }
        }
        __syncthreads();
    }
}

extern "C" void kernel_launch(void* const* d_in, const int* in_sizes, int n_in,
                              void* d_out, int out_size, void* d_ws, size_t ws_size,
                              hipStream_t stream) {
    const float* x         = (const float*)d_in[0];
    const float* lag_embed = (const float*)d_in[1];
    const float* val_w     = (const float*)d_in[2];
    const float* val_b     = (const float*)d_in[3];
    const float* conv_w    = (const float*)d_in[4];
    const float* conv_b    = (const float*)d_in[5];
    const float* ctx_w     = (const float*)d_in[6];
    const float* ctx_b     = (const float*)d_in[7];
    const float* wq        = (const float*)d_in[8];
    const float* wk        = (const float*)d_in[9];
    const float* bias_w    = (const float*)d_in[10];
    const float* bias_b    = (const float*)d_in[11];

    char* wsb = (char*)d_ws;
    double* T2  = (double*)wsb;     // 16384 d
    double* g   = T2 + 16384;       // 1152
    double* u   = g + 1152;         // 128
    double* c1  = u + 128;          // 128
    double* gbT = c1 + 128;         // 2304
    double* cbv = gbT + 2304;       // 256
    double* cst = cbv + 256;        // 20   (f64 region ends @ byte 162976)
    int* wcnt  = (int*)(wsb + 163840);
    int* wlist = wcnt + 1;          // WCAP=16384 ints, ends @ byte 229380
    float* ctx_wT  = (float*)(wsb + 229504);   // 16384 f
    float* wqT     = ctx_wT + 16384;           // 16384 f
    float* conv_wT = wqT + 16384;              // 1152 f
    float* baseT   = conv_wT + 1152;           // 32768 f, ends @ byte 496256

    float* muOut = (float*)d_out;
    float* wOut  = muOut + BQ * TQ;

    hipLaunchKernelGGL(pk1, dim3(D + 2), dim3(D), 0, stream, wk, wq, ctx_w, bias_w, T2, u, wcnt);
    hipLaunchKernelGGL(pk2, dim3(D), dim3(D), 0, stream, T2, ctx_w, conv_w, conv_b, ctx_b, g, c1);
    hipLaunchKernelGGL(pk3, dim3(LQ + 1), dim3(D), 0, stream,
                       lag_embed, val_b, val_w, conv_w, conv_b, ctx_b, bias_w, bias_b,
                       g, c1, u, gbT, cbv, cst);
    hipLaunchKernelGGL(pk4, dim3(D), dim3(LQ), 0, stream,
                       ctx_w, wq, conv_w, val_b, lag_embed, ctx_wT, wqT, conv_wT, baseT);
    hipLaunchKernelGGL(lag_main, dim3(BQ * TQ / 16), dim3(256), 0, stream,
                       x, gbT, cbv, cst, muOut, wOut, wcnt, wlist);
    hipLaunchKernelGGL(fixer, dim3(256), dim3(256), 0, stream,
                       x, wk, val_w, conv_b, ctx_b, bias_w, bias_b,
                       ctx_wT, wqT, conv_wT, baseT, wcnt, wlist, muOut, wOut);
}

// Round 7
// 117.983 us; speedup vs baseline: 2.0040x; 2.0040x over previous
//
#include <hip/hip_runtime.h>
#include <math.h>

#define D   128
#define LQ  256
#define KCQ 9
#define BQ  8
#define TQ  4096
#define RISK_DELTA 2e-5f
#define WCAP 16384

// ---------------- precompute kernels (weights-only, tiny, all-double) ----------------
__global__ void pk1(const float* __restrict__ wk, const float* __restrict__ wq,
                    const float* __restrict__ ctx_w, const float* __restrict__ bias_w,
                    double* __restrict__ T2, double* __restrict__ u, int* __restrict__ wcnt) {
    int e = threadIdx.x;
    if (blockIdx.x < D) {
        int d = blockIdx.x;
        double acc = 0.0;
        for (int j = 0; j < D; ++j)
            acc += (double)wk[j * D + d] * (double)wq[j * D + e];
        T2[d * D + e] = acc;
    } else if (blockIdx.x == D) {
        double acc = 0.0;
        for (int dd = 0; dd < D; ++dd)
            acc += (double)bias_w[dd] * (double)ctx_w[dd * D + e];
        u[e] = acc;
    } else {
        if (e == 0) *wcnt = 0;
    }
}

__global__ void pk2(const double* __restrict__ T2, const float* __restrict__ ctx_w,
                    const float* __restrict__ conv_w, const float* __restrict__ conv_b,
                    const float* __restrict__ ctx_b,
                    double* __restrict__ g, double* __restrict__ c1) {
    __shared__ double row[D];
    int d = blockIdx.x, e = threadIdx.x;
    double acc = 0.0;
    for (int j = 0; j < D; ++j)
        acc += T2[d * D + j] * (double)ctx_w[j * D + e];
    row[e] = acc;
    __syncthreads();
    if (e < KCQ) {
        double a = 0.0;
        for (int q = 0; q < D; ++q) a += row[q] * (double)conv_w[q * KCQ + e];
        g[e * D + d] = a;           // tap-major: g[k][d]
    } else if (e == KCQ) {
        double a = 0.0;
        for (int q = 0; q < D; ++q) a += row[q] * (double)conv_b[q];
        for (int q = 0; q < D; ++q) a += T2[d * D + q] * (double)ctx_b[q];
        c1[d] = a;
    }
}

__global__ void pk3(const float* __restrict__ lag_embed, const float* __restrict__ val_b,
                    const float* __restrict__ val_w, const float* __restrict__ conv_w,
                    const float* __restrict__ conv_b, const float* __restrict__ ctx_b,
                    const float* __restrict__ bias_w, const float* __restrict__ bias_b,
                    const double* __restrict__ g, const double* __restrict__ c1,
                    const double* __restrict__ u,
                    double* __restrict__ gbT, double* __restrict__ cbv, double* __restrict__ cst) {
    int tid = threadIdx.x;
    if (blockIdx.x < LQ) {
        __shared__ double bl[D];
        int l = blockIdx.x;
        bl[tid] = (double)val_b[tid] + (double)lag_embed[(l + 1) * D + tid];
        __syncthreads();
        if (tid < KCQ) {
            double a = 0.0;
            for (int q = 0; q < D; ++q) a += bl[q] * g[tid * D + q];
            gbT[tid * LQ + l] = a;
        } else if (tid == KCQ) {
            double a = 0.0;
            for (int q = 0; q < D; ++q) a += bl[q] * c1[q];
            cbv[l] = a;
        }
    } else {
        if (tid < KCQ) {
            double a = 0.0, a2 = 0.0;
            for (int q = 0; q < D; ++q) a  += g[tid * D + q] * (double)val_w[q];
            for (int q = 0; q < D; ++q) a2 += u[q] * (double)conv_w[q * KCQ + tid];
            cst[tid]      = a;    // sk[k]
            cst[10 + tid] = a2;   // hk[k]
        } else if (tid == KCQ) {
            double a = 0.0, a2 = 0.0;
            for (int q = 0; q < D; ++q) a  += c1[q] * (double)val_w[q];
            for (int q = 0; q < D; ++q) a2 += u[q] * (double)conv_b[q];
            for (int q = 0; q < D; ++q) a2 += (double)bias_w[q] * (double)ctx_b[q];
            cst[9]  = a;                          // ssc
            cst[19] = a2 + (double)bias_b[0];     // hc (incl. bias_b)
        }
    }
}

// pk4: transposed f32 tables so the fixer's loads are lane-coalesced.
__global__ void pk4(const float* __restrict__ ctx_w, const float* __restrict__ wq,
                    const float* __restrict__ conv_w, const float* __restrict__ val_b,
                    const float* __restrict__ lag_embed,
                    float* __restrict__ ctx_wT, float* __restrict__ wqT,
                    float* __restrict__ conv_wT, float* __restrict__ baseT) {
    int d2 = blockIdx.x;        // 0..127
    int tid = threadIdx.x;      // 0..255
    if (tid < D) {
        ctx_wT[d2 * D + tid] = ctx_w[tid * D + d2];
        wqT[d2 * D + tid]    = wq[tid * D + d2];
        if (d2 < KCQ) conv_wT[d2 * D + tid] = conv_w[tid * KCQ + d2];
    }
    // baseT[d2][l] = f32(val_b[d2] + lag_embed[l+1][d2]) — same __fadd_rn as fixer uses
    baseT[d2 * LQ + tid] = __fadd_rn(val_b[d2], lag_embed[(size_t)(tid + 1) * D + d2]);
}

// ---------------- main kernel (round-5 version): 1 wave per row, 4 rows/block ------
// Lane owns l = l0..l0+3 (l0 = lane*4): float4 LDS reads + float4 w stores.
__global__ __launch_bounds__(256, 4) void lag_main(
    const float* __restrict__ x, const double* __restrict__ gbT,
    const double* __restrict__ cbv, const double* __restrict__ cst,
    float* __restrict__ muOut, float* __restrict__ wOut,
    int* __restrict__ wcnt, int* __restrict__ wlist) {
    __shared__ float sgb[KCQ * LQ];
    __shared__ float scb[LQ];
    __shared__ float sc[20];
    int tid = threadIdx.x;
    #pragma unroll
    for (int i = 0; i < KCQ; ++i) sgb[i * LQ + tid] = (float)gbT[i * LQ + tid];
    scb[tid] = (float)cbv[tid];
    if (tid < 20) sc[tid] = (float)cst[tid];
    __syncthreads();

    int wave = tid >> 6, lane = tid & 63;
    int row = blockIdx.x * 4 + wave;
    int b = row >> 12;
    int t = row & (TQ - 1);
    const float* xb = x + b * TQ;

    float xw[KCQ];
    #pragma unroll
    for (int k = 0; k < KCQ; ++k) {
        int idx = t - 8 + k;
        xw[k] = (idx >= 0) ? xb[idx] : 0.f;
    }
    float s = sc[9], bias = sc[19];
    #pragma unroll
    for (int k = 0; k < KCQ; ++k) {
        s    = fmaf(sc[k],      xw[k], s);
        bias = fmaf(sc[10 + k], xw[k], bias);
    }

    int l0 = lane * 4;
    float xlag[4];
    #pragma unroll
    for (int i = 0; i < 4; ++i) {
        int idx = t - 1 - (l0 + i);
        xlag[i] = (idx >= 0) ? xb[idx] : 0.f;
    }

    float4 cb4 = *reinterpret_cast<const float4*>(&scb[l0]);
    float lg[4] = {cb4.x, cb4.y, cb4.z, cb4.w};
    #pragma unroll
    for (int k = 0; k < KCQ; ++k) {
        float4 g4 = *reinterpret_cast<const float4*>(&sgb[k * LQ + l0]);
        lg[0] = fmaf(g4.x, xw[k], lg[0]);
        lg[1] = fmaf(g4.y, xw[k], lg[1]);
        lg[2] = fmaf(g4.z, xw[k], lg[2]);
        lg[3] = fmaf(g4.w, xw[k], lg[3]);
    }
    #pragma unroll
    for (int i = 0; i < 4; ++i) lg[i] = fmaf(xlag[i], s, lg[i]);

    // top-9 extraction (f32): v1 (mx), v8 (thr), v9 (risk gap)
    const float NEG_INF = -__builtin_inff();
    float wl0 = lg[0], wl1 = lg[1], wl2 = lg[2], wl3 = lg[3];
    float mx = 0.f, thr = 0.f, v9 = 0.f;
    #pragma unroll
    for (int it = 0; it < 9; ++it) {
        float lm = fmaxf(fmaxf(wl0, wl1), fmaxf(wl2, wl3));
        float m = lm;
        #pragma unroll
        for (int off = 32; off >= 1; off >>= 1)
            m = fmaxf(m, __shfl_xor(m, off, 64));
        if (it == 0) mx = m;
        if (it == 7) thr = m;
        if (it == 8) v9 = m;
        if (it < 8) {
            unsigned long long ball = __ballot(lm == m);
            int leader = __ffsll(ball) - 1;
            if (lane == leader) {
                if (wl0 == m)      wl0 = NEG_INF;
                else if (wl1 == m) wl1 = NEG_INF;
                else if (wl2 == m) wl2 = NEG_INF;
                else               wl3 = NEG_INF;
            }
        }
    }

    if ((thr - v9) < RISK_DELTA) {
        if (lane == 0) {
            int pos = atomicAdd(wcnt, 1);
            if (pos < WCAP) wlist[pos] = row;
        }
        return;
    }

    float p[4], psum = 0.f, pmu = 0.f;
    #pragma unroll
    for (int j = 0; j < 4; ++j) {
        p[j] = (lg[j] >= thr) ? __expf(lg[j] - mx) : 0.f;
        psum += p[j];
        pmu = fmaf(p[j], xlag[j], pmu);
    }
    #pragma unroll
    for (int off = 32; off >= 1; off >>= 1) {
        psum += __shfl_xor(psum, off, 64);
        pmu  += __shfl_xor(pmu,  off, 64);
    }
    float inv = 1.f / psum;
    float4 wo = make_float4(p[0] * inv, p[1] * inv, p[2] * inv, p[3] * inv);
    *reinterpret_cast<float4*>(&wOut[(size_t)row * LQ + l0]) = wo;
    if (lane == 0) muOut[row] = fmaf(pmu, inv, bias);
}

// ---------------- fixer: np-faithful fp32 pipeline, load-batched ----------
// Arithmetic identical to round 4/5/6 (sequential f32 FMA, ascending index —
// the proven arbiter-matcher). Only change: 16-wide manual load batching so
// each d2-chunk issues 16 independent coalesced loads before the FMA chain.
__global__ __launch_bounds__(256) void fixer(
    const float* __restrict__ x, const float* __restrict__ wk,
    const float* __restrict__ val_w, const float* __restrict__ conv_b,
    const float* __restrict__ ctx_b, const float* __restrict__ bias_w,
    const float* __restrict__ bias_b,
    const float* __restrict__ ctx_wT, const float* __restrict__ wqT,
    const float* __restrict__ conv_wT, const float* __restrict__ baseT,
    const int* __restrict__ wcnt, const int* __restrict__ wlist,
    float* __restrict__ muOut, float* __restrict__ wOut) {
    __shared__ float sxw[8][KCQ];
    __shared__ float sctxc[8][D];
    __shared__ float sctxp[8][D];
    __shared__ float sq[8][D];
    __shared__ float sqk[8][D];
    __shared__ float ssv[8];
    __shared__ float sbd[8];
    __shared__ float slog[8][LQ];
    __shared__ int   srow[8];

    int cnt = *wcnt;
    if (cnt > WCAP) cnt = WCAP;
    int ngroups = (cnt + 7) >> 3;
    int tid = threadIdx.x;

    for (int gi = blockIdx.x; gi < ngroups; gi += gridDim.x) {
        if (tid < 8) {
            int idx = gi * 8 + tid;
            if (idx >= cnt) idx = cnt - 1;   // pad with last row (duplicate write is benign)
            srow[tid] = wlist[idx];
        }
        __syncthreads();
        if (tid < 8 * KCQ) {
            int g = tid / KCQ, k = tid % KCQ;
            int row = srow[g]; int b = row >> 12, t = row & (TQ - 1);
            int ii = t - 8 + k;
            sxw[g][k] = (ii >= 0) ? x[b * TQ + ii] : 0.f;
        }
        __syncthreads();

        // stage 1: causal conv — sequential f32 FMA over k (9 taps, fully unrolled)
        {
            int d = tid & (D - 1), gh = tid >> 7;
            float cw[KCQ];
            #pragma unroll
            for (int k = 0; k < KCQ; ++k) cw[k] = conv_wT[k * D + d];
            for (int g = gh * 4; g < gh * 4 + 4; ++g) {
                float a = 0.f;
                #pragma unroll
                for (int k = 0; k < KCQ; ++k)
                    a = fmaf(cw[k], sxw[g][k], a);
                sctxc[g][d] = __fadd_rn(a, conv_b[d]);
            }
        }
        __syncthreads();

        // stage 2: ctx_proj — sequential f32 FMA over d2, 16-wide load batches
        {
            int e = tid & (D - 1), gh = tid >> 7, g0 = gh * 4;
            float a0 = 0.f, a1 = 0.f, a2 = 0.f, a3 = 0.f;
            for (int d2 = 0; d2 < D; d2 += 16) {
                float wv[16];
                #pragma unroll
                for (int u2 = 0; u2 < 16; ++u2) wv[u2] = ctx_wT[(d2 + u2) * D + e];
                #pragma unroll
                for (int u2 = 0; u2 < 16; ++u2) {
                    a0 = fmaf(wv[u2], sctxc[g0 + 0][d2 + u2], a0);
                    a1 = fmaf(wv[u2], sctxc[g0 + 1][d2 + u2], a1);
                    a2 = fmaf(wv[u2], sctxc[g0 + 2][d2 + u2], a2);
                    a3 = fmaf(wv[u2], sctxc[g0 + 3][d2 + u2], a3);
                }
            }
            float cb = ctx_b[e];
            sctxp[g0 + 0][e] = __fadd_rn(a0, cb);
            sctxp[g0 + 1][e] = __fadd_rn(a1, cb);
            sctxp[g0 + 2][e] = __fadd_rn(a2, cb);
            sctxp[g0 + 3][e] = __fadd_rn(a3, cb);
        }
        __syncthreads();

        // stage 3: q = ctx @ wq.T — sequential f32 FMA over e2, 16-wide load batches
        {
            int a = tid & (D - 1), gh = tid >> 7, g0 = gh * 4;
            float a0 = 0.f, a1 = 0.f, a2 = 0.f, a3 = 0.f;
            for (int e2 = 0; e2 < D; e2 += 16) {
                float wv[16];
                #pragma unroll
                for (int u2 = 0; u2 < 16; ++u2) wv[u2] = wqT[(e2 + u2) * D + a];
                #pragma unroll
                for (int u2 = 0; u2 < 16; ++u2) {
                    a0 = fmaf(wv[u2], sctxp[g0 + 0][e2 + u2], a0);
                    a1 = fmaf(wv[u2], sctxp[g0 + 1][e2 + u2], a1);
                    a2 = fmaf(wv[u2], sctxp[g0 + 2][e2 + u2], a2);
                    a3 = fmaf(wv[u2], sctxp[g0 + 3][e2 + u2], a3);
                }
            }
            sq[g0 + 0][a] = a0;
            sq[g0 + 1][a] = a1;
            sq[g0 + 2][a] = a2;
            sq[g0 + 3][a] = a3;
        }
        __syncthreads();

        // stage 4: qk = q @ wk — sequential f32 FMA over a2, 16-wide load batches
        {
            int d = tid & (D - 1), gh = tid >> 7, g0 = gh * 4;
            float a0 = 0.f, a1 = 0.f, a2 = 0.f, a3 = 0.f;
            for (int a2i = 0; a2i < D; a2i += 16) {
                float wv[16];
                #pragma unroll
                for (int u2 = 0; u2 < 16; ++u2) wv[u2] = wk[(a2i + u2) * D + d];
                #pragma unroll
                for (int u2 = 0; u2 < 16; ++u2) {
                    a0 = fmaf(wv[u2], sq[g0 + 0][a2i + u2], a0);
                    a1 = fmaf(wv[u2], sq[g0 + 1][a2i + u2], a1);
                    a2 = fmaf(wv[u2], sq[g0 + 2][a2i + u2], a2);
                    a3 = fmaf(wv[u2], sq[g0 + 3][a2i + u2], a3);
                }
            }
            sqk[g0 + 0][d] = a0;
            sqk[g0 + 1][d] = a1;
            sqk[g0 + 2][d] = a2;
            sqk[g0 + 3][d] = a3;
        }
        __syncthreads();

        // s = qk·val_w ; biasdot = ctxp·bias_w — sequential f32 FMA, batched loads
        if (tid < 8) {
            int g = tid;
            float a = 0.f;
            for (int d2 = 0; d2 < D; d2 += 16) {
                float vv[16];
                #pragma unroll
                for (int u2 = 0; u2 < 16; ++u2) vv[u2] = val_w[d2 + u2];
                #pragma unroll
                for (int u2 = 0; u2 < 16; ++u2) a = fmaf(sqk[g][d2 + u2], vv[u2], a);
            }
            ssv[g] = a;
        } else if (tid < 16) {
            int g = tid - 8;
            float a = 0.f;
            for (int e2 = 0; e2 < D; e2 += 16) {
                float vv[16];
                #pragma unroll
                for (int u2 = 0; u2 < 16; ++u2) vv[u2] = bias_w[e2 + u2];
                #pragma unroll
                for (int u2 = 0; u2 < 16; ++u2) a = fmaf(sctxp[g][e2 + u2], vv[u2], a);
            }
            sbd[g] = a;
        }
        __syncthreads();

        // logits: blog[l] = Σ_d baseT[d][l]·qk[d] sequential f32 FMA, batched loads;
        // logit = f32(xlag*s) + blog
        {
            int l = tid;
            float c0 = 0.f, c1a = 0.f, c2 = 0.f, c3 = 0.f, c4 = 0.f, c5 = 0.f, c6 = 0.f, c7 = 0.f;
            for (int d2 = 0; d2 < D; d2 += 16) {
                float bd[16];
                #pragma unroll
                for (int u2 = 0; u2 < 16; ++u2) bd[u2] = baseT[(d2 + u2) * LQ + l];
                #pragma unroll
                for (int u2 = 0; u2 < 16; ++u2) {
                    c0 = fmaf(bd[u2], sqk[0][d2 + u2], c0);
                    c1a = fmaf(bd[u2], sqk[1][d2 + u2], c1a);
                    c2 = fmaf(bd[u2], sqk[2][d2 + u2], c2);
                    c3 = fmaf(bd[u2], sqk[3][d2 + u2], c3);
                    c4 = fmaf(bd[u2], sqk[4][d2 + u2], c4);
                    c5 = fmaf(bd[u2], sqk[5][d2 + u2], c5);
                    c6 = fmaf(bd[u2], sqk[6][d2 + u2], c6);
                    c7 = fmaf(bd[u2], sqk[7][d2 + u2], c7);
                }
            }
            float accs[8] = {c0, c1a, c2, c3, c4, c5, c6, c7};
            #pragma unroll
            for (int g = 0; g < 8; ++g) {
                int row = srow[g]; int b = row >> 12, t = row & (TQ - 1);
                int ii = t - 1 - l;
                float xl = (ii >= 0) ? x[b * TQ + ii] : 0.f;
                slog[g][l] = __fadd_rn(__fmul_rn(xl, ssv[g]), accs[g]);
            }
        }
        __syncthreads();

        // per-row f32 top-8 + f32 softmax + writes; wave handles 2 rows
        {
            int wave = tid >> 6, lane = tid & 63;
            for (int gg = wave * 2; gg < wave * 2 + 2; ++gg) {
                float lv0 = slog[gg][lane], lv1 = slog[gg][lane + 64];
                float lv2 = slog[gg][lane + 128], lv3 = slog[gg][lane + 192];
                const float NEG_INF = -__builtin_inff();
                float w0 = lv0, w1 = lv1, w2 = lv2, w3 = lv3;
                float mx = 0.f, thr = 0.f;
                #pragma unroll
                for (int it = 0; it < 8; ++it) {
                    float lm = fmaxf(fmaxf(w0, w1), fmaxf(w2, w3));
                    float m = lm;
                    #pragma unroll
                    for (int off = 32; off >= 1; off >>= 1)
                        m = fmaxf(m, __shfl_xor(m, off, 64));
                    if (it == 0) mx = m;
                    thr = m;
                    if (it < 7) {
                        unsigned long long ball = __ballot(lm == m);
                        int leader = __ffsll(ball) - 1;
                        if (lane == leader) {
                            if (w0 == m)      w0 = NEG_INF;
                            else if (w1 == m) w1 = NEG_INF;
                            else if (w2 == m) w2 = NEG_INF;
                            else              w3 = NEG_INF;
                        }
                    }
                }
                int row = srow[gg]; int b = row >> 12, t = row & (TQ - 1);
                float p[4], xlg[4];
                double ps = 0.0;
                float lvs[4] = {lv0, lv1, lv2, lv3};
                #pragma unroll
                for (int j = 0; j < 4; ++j) {
                    int l = lane + 64 * j;
                    int ii = t - 1 - l;
                    xlg[j] = (ii >= 0) ? x[b * TQ + ii] : 0.f;
                    p[j] = (lvs[j] >= thr) ? (float)exp((double)__fsub_rn(lvs[j], mx)) : 0.f;
                    ps += (double)p[j];
                }
                #pragma unroll
                for (int off = 32; off >= 1; off >>= 1)
                    ps += __shfl_xor(ps, off, 64);
                float psf = (float)ps;
                double mud = 0.0;
                #pragma unroll
                for (int j = 0; j < 4; ++j) {
                    float wv = __fdiv_rn(p[j], psf);
                    wOut[(size_t)row * LQ + lane + 64 * j] = wv;
                    mud += (double)__fmul_rn(wv, xlg[j]);
                }
                #pragma unroll
                for (int off = 32; off >= 1; off >>= 1)
                    mud += __shfl_xor(mud, off, 64);
                if (lane == 0) {
                    float m1 = (float)mud;
                    m1 = __fadd_rn(m1, sbd[gg]);
                    m1 = __fadd_rn(m1, bias_b[0]);
                    muOut[row] = m1;
                }
            }
        }
        __syncthreads();
    }
}

extern "C" void kernel_launch(void* const* d_in, const int* in_sizes, int n_in,
                              void* d_out, int out_size, void* d_ws, size_t ws_size,
                              hipStream_t stream) {
    const float* x         = (const float*)d_in[0];
    const float* lag_embed = (const float*)d_in[1];
    const float* val_w     = (const float*)d_in[2];
    const float* val_b     = (const float*)d_in[3];
    const float* conv_w    = (const float*)d_in[4];
    const float* conv_b    = (const float*)d_in[5];
    const float* ctx_w     = (const float*)d_in[6];
    const float* ctx_b     = (const float*)d_in[7];
    const float* wq        = (const float*)d_in[8];
    const float* wk        = (const float*)d_in[9];
    const float* bias_w    = (const float*)d_in[10];
    const float* bias_b    = (const float*)d_in[11];

    char* wsb = (char*)d_ws;
    double* T2  = (double*)wsb;     // 16384 d
    double* g   = T2 + 16384;       // 1152
    double* u   = g + 1152;         // 128
    double* c1  = u + 128;          // 128
    double* gbT = c1 + 128;         // 2304
    double* cbv = gbT + 2304;       // 256
    double* cst = cbv + 256;        // 20   (f64 region ends @ byte 162976)
    int* wcnt  = (int*)(wsb + 163840);
    int* wlist = wcnt + 1;          // WCAP=16384 ints
    float* ctx_wT  = (float*)(wsb + 229504);   // 16384 f
    float* wqT     = ctx_wT + 16384;           // 16384 f
    float* conv_wT = wqT + 16384;              // 1152 f
    float* baseT   = conv_wT + 1152;           // 32768 f, ends @ byte 496256

    float* muOut = (float*)d_out;
    float* wOut  = muOut + BQ * TQ;

    hipLaunchKernelGGL(pk1, dim3(D + 2), dim3(D), 0, stream, wk, wq, ctx_w, bias_w, T2, u, wcnt);
    hipLaunchKernelGGL(pk2, dim3(D), dim3(D), 0, stream, T2, ctx_w, conv_w, conv_b, ctx_b, g, c1);
    hipLaunchKernelGGL(pk3, dim3(LQ + 1), dim3(D), 0, stream,
                       lag_embed, val_b, val_w, conv_w, conv_b, ctx_b, bias_w, bias_b,
                       g, c1, u, gbT, cbv, cst);
    hipLaunchKernelGGL(pk4, dim3(D), dim3(LQ), 0, stream,
                       ctx_w, wq, conv_w, val_b, lag_embed, ctx_wT, wqT, conv_wT, baseT);
    hipLaunchKernelGGL(lag_main, dim3(BQ * TQ / 4), dim3(256), 0, stream,
                       x, gbT, cbv, cst, muOut, wOut, wcnt, wlist);
    hipLaunchKernelGGL(fixer, dim3(256), dim3(256), 0, stream,
                       x, wk, val_w, conv_b, ctx_b, bias_w, bias_b,
                       ctx_wT, wqT, conv_wT, baseT, wcnt, wlist, muOut, wOut);
}